// Round 8
// baseline (37.295 us; speedup 1.0000x reference)
//
#include <hip/hip_runtime.h>

// GRNN (Nadaraya-Watson, Gaussian kernel) — bf16 MFMA, 256x256 tile,
// 16 waves (64x64 wave tile, acc=64 VGPR -> 4 waves/SIMD), BK=32
// double-buffer (64 KB LDS), counted-vmcnt schedule, conflict-free
// unswizzled LDS (64B rows spread banks uniformly).
// X [4096,256], X_train [8192,256], y_train [8192,1] -> out [4096]
// w = exp(-12.5*d2); exp2(K1*||x||^2) row factor cancels in num/den.

#define N_Q 4096
#define N_T 8192
#define DIM 256
#define QB 256
#define TB 256
#define BK 32
#define NKT (DIM / BK)            // 8
#define TILE_B (256 * BK * 2)     // 16384 B per (256-row, 32-k) bf16 tile
#define NC (N_T / TB)             // 32 partial slices
#define NXB (N_T / TB)            // 32
#define NYB (N_Q / QB)            // 16
#define K1f (-18.033688011112042f)   // -12.5 * log2(e)
#define K2f ( 36.067376022224084f)   //  25.0 * log2(e)

typedef __attribute__((ext_vector_type(8))) short bf16x8;
typedef __attribute__((ext_vector_type(4))) float f32x4;

__device__ __forceinline__ void gload16(const void* g, void* l) {
    __builtin_amdgcn_global_load_lds(
        (const __attribute__((address_space(1))) unsigned*)g,
        (__attribute__((address_space(3))) unsigned*)l, 16, 0, 0);
}

__device__ __forceinline__ unsigned short bft(float f) {
    return (unsigned short)(__builtin_bit_cast(unsigned, f) >> 16);
}

#define WVM2() asm volatile("s_waitcnt vmcnt(2)" ::: "memory")
#define WVM0() asm volatile("s_waitcnt vmcnt(0)" ::: "memory")
#define WLG0() asm volatile("s_waitcnt lgkmcnt(0)" ::: "memory")
#define BARX() __builtin_amdgcn_s_barrier()
#define SFEN() __builtin_amdgcn_sched_barrier(0)

// ---- prep: train-row norms (prescaled by K1) + bf16 tiled copies -----------
// Tile (rt=row/256, kt=k/32): byte = tile*16384 + (row&255)*64 + (k&31)*2.
__global__ __launch_bounds__(256) void grnn_prep(
    const float* __restrict__ X, const float* __restrict__ XT,
    float* __restrict__ xt2s,
    unsigned short* __restrict__ Xb, unsigned short* __restrict__ XTb)
{
    int wave = blockIdx.x * 4 + (threadIdx.x >> 6);
    int lane = threadIdx.x & 63;
    if (wave >= N_Q + N_T) return;
    const float* src; unsigned short* tdst; int row; bool train;
    if (wave < N_Q) { row = wave;       src = X  + (size_t)row * DIM; tdst = Xb;  train = false; }
    else            { row = wave - N_Q; src = XT + (size_t)row * DIM; tdst = XTb; train = true; }
    float4 v = ((const float4*)src)[lane];   // k = 4*lane .. +3

    int kt = lane >> 3;              // k-tile 0..7
    int rl = row & 255;
    size_t byte = (size_t)((row >> 8) * NKT + kt) * TILE_B
                + (size_t)rl * 64 + (lane & 7) * 8;
    ushort4 b4;
    b4.x = bft(v.x); b4.y = bft(v.y); b4.z = bft(v.z); b4.w = bft(v.w);
    *(ushort4*)((char*)tdst + byte) = b4;

    if (train) {
        float s = v.x*v.x + v.y*v.y + v.z*v.z + v.w*v.w;
        #pragma unroll
        for (int off = 32; off > 0; off >>= 1) s += __shfl_xor(s, off);
        if (lane == 0) xt2s[row] = K1f * s;
    }
}

// ---- main: 256x256 tile, 16 waves, BK=32 counted-vmcnt double-buffer -------
__global__ __launch_bounds__(1024, 4) void grnn_mfma4(
    const unsigned short* __restrict__ Xb, const unsigned short* __restrict__ XTb,
    const float* __restrict__ y, const float* __restrict__ xt2s,
    float* __restrict__ pnum, float* __restrict__ pden)
{
    __shared__ char lds[2][2][TILE_B];   // [buf][A=query / B=train] = 64 KB

    // XCD-chunked swizzle: XCD k owns bx in [k*4, k*4+4) across all by.
    const int bid = blockIdx.x;
    const int xcd = bid & 7;
    const int idx = bid >> 3;            // 0..63
    const int bx  = xcd * 4 + (idx & 3); // 0..31
    const int by  = idx >> 2;            // 0..15

    const int t    = threadIdx.x;
    const int lane = t & 63;
    const int wid  = t >> 6;             // 0..15
    const int wm   = wid >> 2;           // 0..3  (m quarter: 64 rows)
    const int wn   = wid & 3;            // 0..3  (n quarter: 64 cols)
    const int qb   = by * QB;
    const int tb   = bx * TB;
    const int fr   = lane & 15;
    const int fq   = lane >> 4;

    const char* gA = (const char*)Xb  + (size_t)(by * NKT) * TILE_B;
    const char* gB = (const char*)XTb + (size_t)(bx * NKT) * TILE_B;

    int arow[4], brow[4];
    #pragma unroll
    for (int f = 0; f < 4; ++f) {
        arow[f] = wm * 64 + f * 16 + fr;
        brow[f] = wn * 64 + f * 16 + fr;
    }

    f32x4 acc[4][4] = {};   // acc[mf][nf]: D rows = train n, cols = query m

    // 1024 threads x 16B = 16 KB = exactly one tile: 1 load per matrix/thread.
    #define STAGE(buf, kt)                                                     \
        do {                                                                   \
            gload16(gA + (size_t)(kt) * TILE_B + t * 16, &lds[buf][0][t * 16]);\
            gload16(gB + (size_t)(kt) * TILE_B + t * 16, &lds[buf][1][t * 16]);\
        } while (0)

    #define COMPUTE(buf)                                                       \
        do {                                                                   \
            bf16x8 af[4], bff[4];                                              \
            _Pragma("unroll")                                                  \
            for (int f = 0; f < 4; ++f)                                        \
                af[f] = *(const bf16x8*)&lds[buf][0][arow[f] * 64 + fq * 16];  \
            _Pragma("unroll")                                                  \
            for (int f = 0; f < 4; ++f)                                        \
                bff[f] = *(const bf16x8*)&lds[buf][1][brow[f] * 64 + fq * 16]; \
            _Pragma("unroll")                                                  \
            for (int mf = 0; mf < 4; ++mf)                                     \
                _Pragma("unroll")                                              \
                for (int nf = 0; nf < 4; ++nf)                                 \
                    acc[mf][nf] = __builtin_amdgcn_mfma_f32_16x16x32_bf16(     \
                        bff[nf], af[mf], acc[mf][nf], 0, 0, 0);                \
        } while (0)

    STAGE(0, 0);
    STAGE(1, 1);                 // 4 loads in flight per wave

    #pragma unroll
    for (int kt = 0; kt < NKT; ++kt) {
        const int buf = kt & 1;
        if (kt == NKT - 1) { WVM0(); } else { WVM2(); }  // kt's tile landed
        BARX(); SFEN();
        __builtin_amdgcn_s_setprio(1);
        COMPUTE(buf);
        __builtin_amdgcn_s_setprio(0);
        if (kt + 2 < NKT) {
            WLG0(); BARX();      // all waves' reads of buf done -> safe to overwrite
            STAGE(buf, kt + 2);  // 2 more loads in flight
        }
    }

    // Epilogue: w' = exp2(K2*c + xt2s[n]); in-lane n-reduce (+2 shfl over fq)
    float nv[4] = {}, dv[4] = {};
    #pragma unroll
    for (int nf = 0; nf < 4; ++nf)
        #pragma unroll
        for (int rr = 0; rr < 4; ++rr) {
            int n = tb + wn * 64 + nf * 16 + fq * 4 + rr;
            float ts = xt2s[n];
            float yy = y[n];
            #pragma unroll
            for (int mf = 0; mf < 4; ++mf) {
                float s = fmaf(K2f, acc[mf][nf][rr], ts);
                float w;
                asm("v_exp_f32 %0, %1" : "=v"(w) : "v"(s));  // 2^s, ->0 underflow
                nv[mf] = fmaf(w, yy, nv[mf]);
                dv[mf] += w;
            }
        }

    #pragma unroll
    for (int mf = 0; mf < 4; ++mf) {
        nv[mf] += __shfl_xor(nv[mf], 16);
        nv[mf] += __shfl_xor(nv[mf], 32);
        dv[mf] += __shfl_xor(dv[mf], 16);
        dv[mf] += __shfl_xor(dv[mf], 32);
    }

    // Cross-wn combine in LDS (overlay buf0: all waves past last buf0 reads),
    // then one slice per block: pnum/pden layout [m][NC].
    float* comb = (float*)&lds[0][0][0];   // [wn][arr][256 rows] = 8 KB
    __syncthreads();                       // everyone done with K-loop LDS
    if (fq == 0) {
        #pragma unroll
        for (int mf = 0; mf < 4; ++mf) {
            int row = wm * 64 + mf * 16 + fr;
            comb[(wn * 2 + 0) * 256 + row] = nv[mf];
            comb[(wn * 2 + 1) * 256 + row] = dv[mf];
        }
    }
    __syncthreads();
    if (t < 512) {
        int row = t & 255;
        int arr = t >> 8;
        float s = comb[(0 * 2 + arr) * 256 + row] + comb[(1 * 2 + arr) * 256 + row]
                + comb[(2 * 2 + arr) * 256 + row] + comb[(3 * 2 + arr) * 256 + row];
        float* dst = arr ? pden : pnum;
        dst[(size_t)(qb + row) * NC + bx] = s;
    }
    #undef STAGE
    #undef COMPUTE
}

// ---- reduce: one wave per output row, coalesced [m][NC] reads --------------
__global__ __launch_bounds__(256) void grnn_reduce(const float* __restrict__ pnum,
                                                   const float* __restrict__ pden,
                                                   float* __restrict__ out) {
    int wv   = blockIdx.x * 4 + (threadIdx.x >> 6);   // 0..4095
    int lane = threadIdx.x & 63;
    float n = 0.f, d = 0.f;
    if (lane < NC) {
        n = pnum[(size_t)wv * NC + lane];
        d = pden[(size_t)wv * NC + lane];
    }
    #pragma unroll
    for (int off = 1; off < 64; off <<= 1) {
        n += __shfl_xor(n, off);
        d += __shfl_xor(d, off);
    }
    if (lane == 0) out[wv] = n / (d + 1e-9f);
}

// ---- fallback path (atomics; only if ws is tiny) ---------------------------
__global__ void grnn_zero(float* __restrict__ ws) {
    int i = blockIdx.x * 256 + threadIdx.x;
    if (i < 2 * N_Q) ws[i] = 0.0f;
}

__global__ __launch_bounds__(256) void grnn_rowsq(const float* __restrict__ X,
                                                  const float* __restrict__ XT,
                                                  float* __restrict__ xq2,
                                                  float* __restrict__ xt2) {
    int wave = blockIdx.x * 4 + (threadIdx.x >> 6);
    int lane = threadIdx.x & 63;
    if (wave >= N_Q + N_T) return;
    const float* src; float* dst;
    if (wave < N_Q) { src = X + (size_t)wave * DIM;          dst = xq2 + wave; }
    else            { src = XT + (size_t)(wave - N_Q) * DIM; dst = xt2 + (wave - N_Q); }
    float4 v = ((const float4*)src)[lane];
    float s = v.x*v.x + v.y*v.y + v.z*v.z + v.w*v.w;
    #pragma unroll
    for (int off = 32; off > 0; off >>= 1) s += __shfl_xor(s, off);
    if (lane == 0) *dst = s;
}

__device__ __forceinline__ unsigned pk_bf16(float lo, float hi) {
    unsigned a = __builtin_bit_cast(unsigned, lo);
    unsigned b = __builtin_bit_cast(unsigned, hi);
    return (b & 0xFFFF0000u) | (a >> 16);
}

__global__ __launch_bounds__(256, 2) void grnn_mfma_atomic(
    const float* __restrict__ X, const float* __restrict__ XT,
    const float* __restrict__ y, const float* __restrict__ xq2,
    const float* __restrict__ xt2,
    float* __restrict__ num, float* __restrict__ den)
{
    __shared__ char lds[2][2][16384];
    const int t = threadIdx.x, lane = t & 63, wid = t >> 6;
    const int wm = wid >> 1, wn = wid & 1;
    const int qb = blockIdx.y * 128, tb = blockIdx.x * 128;
    const int srow = t >> 3, sslot = t & 7, sswz = sslot ^ (srow & 7);
    const float* Ag = X  + (size_t)(qb + srow) * DIM + sslot * 8;
    const float* Bg = XT + (size_t)(tb + srow) * DIM + sslot * 8;
    float4 ra[4][2], rb[4][2];

    #define LOADT(kt)                                                          \
        _Pragma("unroll")                                                      \
        for (int p = 0; p < 4; ++p) {                                          \
            const float* ga = Ag + (size_t)(p * 32) * DIM + (kt) * 64;         \
            const float* gb = Bg + (size_t)(p * 32) * DIM + (kt) * 64;         \
            ra[p][0] = *(const float4*)ga;  ra[p][1] = *(const float4*)(ga+4); \
            rb[p][0] = *(const float4*)gb;  rb[p][1] = *(const float4*)(gb+4); \
        }
    #define WRITET(buf)                                                        \
        _Pragma("unroll")                                                      \
        for (int p = 0; p < 4; ++p) {                                          \
            int byte = (srow + p * 32) * 128 + (sswz << 4);                    \
            int4 wa, wb;                                                       \
            wa.x = pk_bf16(ra[p][0].x, ra[p][0].y);                            \
            wa.y = pk_bf16(ra[p][0].z, ra[p][0].w);                            \
            wa.z = pk_bf16(ra[p][1].x, ra[p][1].y);                            \
            wa.w = pk_bf16(ra[p][1].z, ra[p][1].w);                            \
            wb.x = pk_bf16(rb[p][0].x, rb[p][0].y);                            \
            wb.y = pk_bf16(rb[p][0].z, rb[p][0].w);                            \
            wb.z = pk_bf16(rb[p][1].x, rb[p][1].y);                            \
            wb.w = pk_bf16(rb[p][1].z, rb[p][1].w);                            \
            *(int4*)&lds[buf][0][byte] = wa;                                   \
            *(int4*)&lds[buf][1][byte] = wb;                                   \
        }

    f32x4 acc[4][4] = {};
    const int fr = lane & 15, fq = lane >> 4;
    int arow[4], brow[4];
    #pragma unroll
    for (int f = 0; f < 4; ++f) { arow[f] = wm*64+f*16+fr; brow[f] = wn*64+f*16+fr; }

    LOADT(0); WRITET(0); __syncthreads();
    for (int kt = 0; kt < 4; ++kt) {
        if (kt + 1 < 4) { LOADT(kt + 1); }
        const int buf = kt & 1;
        #pragma unroll
        for (int kk = 0; kk < 2; ++kk) {
            bf16x8 af[4], bf[4];
            #pragma unroll
            for (int f = 0; f < 4; ++f) {
                int sa = (fq + kk * 4) ^ (arow[f] & 7);
                int sb = (fq + kk * 4) ^ (brow[f] & 7);
                af[f] = *(const bf16x8*)&lds[buf][0][arow[f] * 128 + (sa << 4)];
                bf[f] = *(const bf16x8*)&lds[buf][1][brow[f] * 128 + (sb << 4)];
            }
            #pragma unroll
            for (int mf = 0; mf < 4; ++mf)
                #pragma unroll
                for (int nf = 0; nf < 4; ++nf)
                    acc[mf][nf] = __builtin_amdgcn_mfma_f32_16x16x32_bf16(
                        af[mf], bf[nf], acc[mf][nf], 0, 0, 0);
        }
        if (kt + 1 < 4) { __syncthreads(); WRITET(buf ^ 1); __syncthreads(); }
    }

    float xq[4][4];
    #pragma unroll
    for (int mf = 0; mf < 4; ++mf)
        #pragma unroll
        for (int r = 0; r < 4; ++r)
            xq[mf][r] = xq2[qb + wm * 64 + mf * 16 + fq * 4 + r];
    float nv[4][4] = {}, dv[4][4] = {};
    #pragma unroll
    for (int nf = 0; nf < 4; ++nf) {
        int n = tb + wn * 64 + nf * 16 + fr;
        float t2 = xt2[n], yvv = y[n];
        #pragma unroll
        for (int mf = 0; mf < 4; ++mf)
            #pragma unroll
            for (int r = 0; r < 4; ++r) {
                float d2 = xq[mf][r] + t2 - 2.0f * acc[mf][nf][r];
                float w  = __expf(-12.5f * d2);
                nv[mf][r] += w * yvv; dv[mf][r] += w;
            }
    }
    #pragma unroll
    for (int off = 1; off < 16; off <<= 1)
        #pragma unroll
        for (int mf = 0; mf < 4; ++mf)
            #pragma unroll
            for (int r = 0; r < 4; ++r) {
                nv[mf][r] += __shfl_xor(nv[mf][r], off);
                dv[mf][r] += __shfl_xor(dv[mf][r], off);
            }
    if (fr == 0) {
        #pragma unroll
        for (int mf = 0; mf < 4; ++mf)
            #pragma unroll
            for (int r = 0; r < 4; ++r) {
                int m = qb + wm * 64 + mf * 16 + fq * 4 + r;
                atomicAdd(&num[m], nv[mf][r]);
                atomicAdd(&den[m], dv[mf][r]);
            }
    }
    #undef LOADT
    #undef WRITET
}

__global__ void grnn_final(const float* __restrict__ num,
                           const float* __restrict__ den,
                           float* __restrict__ out) {
    int i = blockIdx.x * 256 + threadIdx.x;
    if (i < N_Q) out[i] = num[i] / (den[i] + 1e-9f);
}

// ---- launch -----------------------------------------------------------------
extern "C" void kernel_launch(void* const* d_in, const int* in_sizes, int n_in,
                              void* d_out, int out_size, void* d_ws, size_t ws_size,
                              hipStream_t stream) {
    const float* X  = (const float*)d_in[0];
    const float* XT = (const float*)d_in[1];
    const float* y  = (const float*)d_in[2];
    float* out = (float*)d_out;
    char*  ws  = (char*)d_ws;

    const size_t off_pnum = 0;                                  // 512 KB
    const size_t off_pden = off_pnum + (size_t)N_Q * NC * 4;    // 512 KB
    const size_t off_xt2  = off_pden + (size_t)N_Q * NC * 4;    // 32 KB
    const size_t off_Xb   = off_xt2  + (size_t)N_T * 4;         // 2 MB (16B-aligned)
    const size_t off_XTb  = off_Xb   + (size_t)N_Q * DIM * 2;   // 4 MB
    const size_t need     = off_XTb  + (size_t)N_T * DIM * 2;   // ~7.05 MB

    if (ws_size >= need) {
        float* pnum = (float*)(ws + off_pnum);
        float* pden = (float*)(ws + off_pden);
        float* xt2s = (float*)(ws + off_xt2);
        unsigned short* Xb  = (unsigned short*)(ws + off_Xb);
        unsigned short* XTb = (unsigned short*)(ws + off_XTb);
        hipLaunchKernelGGL(grnn_prep, dim3((N_Q + N_T) / 4), dim3(256), 0, stream,
                           X, XT, xt2s, Xb, XTb);
        hipLaunchKernelGGL(grnn_mfma4, dim3(NXB * NYB), dim3(1024), 0, stream,
                           Xb, XTb, y, xt2s, pnum, pden);
        hipLaunchKernelGGL(grnn_reduce, dim3(N_Q / 4), dim3(256), 0, stream,
                           pnum, pden, out);
    } else {
        float* num = (float*)ws;
        float* den = num + N_Q;
        float* xq2 = num + 2 * N_Q;
        float* xt2 = num + 3 * N_Q;
        hipLaunchKernelGGL(grnn_zero, dim3((2 * N_Q + 255) / 256), dim3(256), 0, stream,
                           (float*)ws);
        hipLaunchKernelGGL(grnn_rowsq, dim3((N_Q + N_T + 3) / 4), dim3(256), 0, stream,
                           X, XT, xq2, xt2);
        hipLaunchKernelGGL(grnn_mfma_atomic, dim3(N_T / 128, N_Q / 128), dim3(256), 0, stream,
                           X, XT, y, xq2, xt2, num, den);
        hipLaunchKernelGGL(grnn_final, dim3((N_Q + 255) / 256), dim3(256), 0, stream,
                           num, den, out);
    }
}